// Round 12
// baseline (451.290 us; speedup 1.0000x reference)
//
#include <hip/hip_runtime.h>

// SparseResidualBlock: bn1->silu->sparseconv1(+t_emb)->bn2->silu->sparseconv2 + (x@res_W+res_b)
// N=50000, FIN=64, FOUT=128, K=27, B=4, TEMB=256. Output f32 [N,128].
//
// R12 = R5's ko-split-4 structure WITHOUT the VGPR cap (R5's 253us was pure
// spill: launch_bounds(256,4) forced 64 VGPR -> 800MB scratch). 6250 waves
// (2x R8), 3 barriers/block total, 56 batched gathers/wave. nbr loaded in
// parallel with mask (no dependent hop). Weights streamed L2-direct per-wave
// (7 taps x 32KB). Waves are the latency-hiding currency (R9/R11 lesson).

#define EPS 1e-5f

typedef __attribute__((ext_vector_type(8))) short s16x8;
typedef __attribute__((ext_vector_type(4))) float f32x4;
typedef __attribute__((ext_vector_type(4))) unsigned short u16x4;

#define RSTRIDE 132   // padded f32 stride for 128-ch rows in LDS reduce

static __device__ __forceinline__ unsigned short f2bf(float f) {
    union { float f; unsigned u; } v; v.f = f;
    unsigned r = v.u + 0x7fffu + ((v.u >> 16) & 1u);   // RTNE
    return (unsigned short)(r >> 16);
}
static __device__ __forceinline__ float silu_d(float x) {
    return x / (1.f + __expf(-x));
}
// mask stored as 1-byte bool (shift 0) or int32 (shift 2)? Probe a byte at a
// non-multiple-of-4 index inside the all-true center row (k=13).
static __device__ __forceinline__ int mask_shift(const unsigned char* mask, int NV) {
    size_t base = (size_t)13 * (size_t)NV;
    int v = ((base & 3) == 3) ? 2 : 1;
    return (mask[base + v] == 1) ? 0 : 2;
}

// ---------------- prep: t_emb + bn2 scale/shift ----------------
__global__ void k_prep_small(const float* __restrict__ t, const float* __restrict__ tW,
                             const float* __restrict__ tb,
                             const float* __restrict__ g2, const float* __restrict__ b2,
                             const float* __restrict__ m2, const float* __restrict__ v2,
                             float* __restrict__ temb, float* __restrict__ sc,
                             float* __restrict__ sh, int B) {
    int tid = threadIdx.x;
    if (tid < B * 128) {
        int b = tid >> 7, o = tid & 127;
        float s = 0.f;
        for (int e = 0; e < 256; ++e) {
            float tv = t[b * 256 + e];
            s += silu_d(tv) * tW[e * 128 + o];
        }
        temb[tid] = s + tb[o];
    }
    if (tid < 128) {
        float rstd = rsqrtf(v2[tid] + EPS);
        float s1 = g2[tid] * rstd;
        sc[tid] = s1;
        sh[tid] = b2[tid] - m2[tid] * s1;
    }
}

// ---------------- prep: shuffle weights to fragment-linear bf16 (16x16x32) ----------------
// frag elem[lane*8+j] = W[ko][fin=ks*32+(lane>>4)*8+j][fout=mt*16+(lane&15)]
__global__ __launch_bounds__(256) void k_shuffle(
        const float* __restrict__ W1, const float* __restrict__ W2,
        const float* __restrict__ rW,
        unsigned short* __restrict__ W1s, unsigned short* __restrict__ W2s,
        unsigned short* __restrict__ rWs) {
    int tid = blockIdx.x * 256 + threadIdx.x;
    const int n1 = 432 * 512, n2 = 864 * 512, n3 = 16 * 512;
    if (tid < n1) {
        int f = tid >> 9, r = tid & 511, lane = r >> 3, j = r & 7;
        int mt = f & 7, fk = f >> 3, ks = fk & 1, ko = fk >> 1;
        int fin = ks * 32 + (lane >> 4) * 8 + j;
        int fout = mt * 16 + (lane & 15);
        W1s[tid] = f2bf(W1[(ko * 64 + fin) * 128 + fout]);
    } else if (tid < n1 + n2) {
        int e = tid - n1;
        int f = e >> 9, r = e & 511, lane = r >> 3, j = r & 7;
        int mt = f & 7, fk = f >> 3, ks = fk & 3, ko = fk >> 2;
        int fin = ks * 32 + (lane >> 4) * 8 + j;
        int fout = mt * 16 + (lane & 15);
        W2s[e] = f2bf(W2[(ko * 128 + fin) * 128 + fout]);
    } else if (tid < n1 + n2 + n3) {
        int e = tid - n1 - n2;
        int f = e >> 9, r = e & 511, lane = r >> 3, j = r & 7;
        int mt = f & 7, ks = f >> 3;
        int fin = ks * 32 + (lane >> 4) * 8 + j;
        int fout = mt * 16 + (lane & 15);
        rWs[e] = f2bf(rW[fin * 128 + fout]);
    }
}

// ---------------- elementwise: h1 = bf16(silu(bn1(x))) ----------------
__global__ __launch_bounds__(256) void k_elem(
        const float* __restrict__ x,
        const float* __restrict__ g1, const float* __restrict__ b1,
        const float* __restrict__ m1, const float* __restrict__ v1,
        unsigned short* __restrict__ h1, int NV) {
    int tid = blockIdx.x * 256 + threadIdx.x;
    if (tid >= NV * 16) return;
    int n = tid >> 4, c = (tid & 15) << 2;
    f32x4 xv = *(const f32x4*)(x + n * 64 + c);
    f32x4 gv = *(const f32x4*)(g1 + c);
    f32x4 bv = *(const f32x4*)(b1 + c);
    f32x4 mv = *(const f32x4*)(m1 + c);
    f32x4 vv = *(const f32x4*)(v1 + c);
    u16x4 ho;
#pragma unroll
    for (int j = 0; j < 4; ++j) {
        float xn = (xv[j] - mv[j]) * rsqrtf(vv[j] + EPS) * gv[j] + bv[j];
        ho[j] = f2bf(silu_d(xn));
    }
    *(u16x4*)(h1 + n * 64 + c) = ho;
}

// ================= conv1: ko-split-4, 32 voxels/block, no VGPR cap =================
// h2in = bf16(silu(bn2(sparseconv(h1,W1) + temb[bidx])))
__global__ __launch_bounds__(256) void k_conv1(
        const unsigned short* __restrict__ h1, const int* __restrict__ nbr,
        const unsigned char* __restrict__ mask, const unsigned short* __restrict__ W1s,
        const float* __restrict__ temb, const int* __restrict__ bidx,
        const float* __restrict__ bn2sc, const float* __restrict__ bn2sh,
        unsigned short* __restrict__ h2in, int NV) {
    const int lane = threadIdx.x & 63;
    const int wave = threadIdx.x >> 6;
    const int g = lane >> 4, col = lane & 15;
    const int nb = blockIdx.x * 32;
    const int v0 = nb + col, v1 = nb + 16 + col;
    const int msh = mask_shift(mask, NV);
    const int sbeg = wave * 7;
    const int scnt = min(7, 27 - sbeg);

    f32x4 acc[2][8];
    const f32x4 z4 = {0.f, 0.f, 0.f, 0.f};
#pragma unroll
    for (int t = 0; t < 2; ++t)
#pragma unroll
        for (int m = 0; m < 8; ++m) acc[t][m] = z4;
    const s16x8 zz = {0, 0, 0, 0, 0, 0, 0, 0};

    // preload nbr+mask in parallel (no dependent hop), select after
    int r0[7], r1[7];
#pragma unroll
    for (int s = 0; s < 7; ++s) {
        r0[s] = -1; r1[s] = -1;
        if (s < scnt) {
            int off = (sbeg + s) * NV;
            if (v0 < NV) {
                int nv = nbr[off + v0];
                bool mm = mask[(size_t)(off + v0) << msh] != 0;
                r0[s] = mm ? nv : -1;
            }
            if (v1 < NV) {
                int nv = nbr[off + v1];
                bool mm = mask[(size_t)(off + v1) << msh] != 0;
                r1[s] = mm ? nv : -1;
            }
        }
    }

#pragma unroll
    for (int s = 0; s < 7; ++s) {
        if (s < scnt) {
            const int ko = sbeg + s;
            const bool m0 = r0[s] >= 0, m1 = r1[s] >= 0;
            const int row0 = m0 ? r0[s] : 0, row1 = m1 ? r1[s] : 0;
#pragma unroll
            for (int ks = 0; ks < 2; ++ks) {
                s16x8 b0 = *(const s16x8*)(h1 + row0 * 64 + ks * 32 + g * 8);
                s16x8 b1 = *(const s16x8*)(h1 + row1 * 64 + ks * 32 + g * 8);
                b0 = m0 ? b0 : zz;
                b1 = m1 ? b1 : zz;
                const unsigned short* wp = W1s + (ko * 2 + ks) * 4096 + lane * 8;
#pragma unroll
                for (int mt = 0; mt < 8; ++mt) {
                    s16x8 a = *(const s16x8*)(wp + mt * 512);
                    acc[0][mt] = __builtin_amdgcn_mfma_f32_16x16x32_bf16(a, b0, acc[0][mt], 0, 0, 0);
                    acc[1][mt] = __builtin_amdgcn_mfma_f32_16x16x32_bf16(a, b1, acc[1][mt], 0, 0, 0);
                }
            }
        }
    }

    // ---- LDS tree reduce: waves 2,3 -> waves 0,1; then cross(0,1) ----
    __shared__ float red[2][2][16 * RSTRIDE];
    const int lbase = col * RSTRIDE + g * 4;
    if (wave >= 2) {
        int p = wave - 2;
#pragma unroll
        for (int t = 0; t < 2; ++t)
#pragma unroll
            for (int mt = 0; mt < 8; ++mt)
                *(f32x4*)&red[p][t][lbase + mt * 16] = acc[t][mt];
    }
    __syncthreads();
    if (wave < 2) {
#pragma unroll
        for (int t = 0; t < 2; ++t)
#pragma unroll
            for (int mt = 0; mt < 8; ++mt)
                acc[t][mt] += *(const f32x4*)&red[wave][t][lbase + mt * 16];
    }
    __syncthreads();
    if (wave == 1) {
#pragma unroll
        for (int mt = 0; mt < 8; ++mt)
            *(f32x4*)&red[0][0][lbase + mt * 16] = acc[0][mt];
    } else if (wave == 0) {
#pragma unroll
        for (int mt = 0; mt < 8; ++mt)
            *(f32x4*)&red[0][1][lbase + mt * 16] = acc[1][mt];
    }
    __syncthreads();

    // ---- epilogue: wave0 -> tile0, wave1 -> tile1 ----
    if (wave < 2) {
        const int t = wave;
        int v = nb + t * 16 + col;
        if (v < NV) {
            int b = bidx[v];
            const float* te = temb + b * 128;
#pragma unroll
            for (int mt = 0; mt < 8; ++mt) {
                int c = mt * 16 + g * 4;
                f32x4 val = acc[t][mt] + *(const f32x4*)&red[0][t][lbase + mt * 16];
                f32x4 tv = *(const f32x4*)(te + c);
                f32x4 sc = *(const f32x4*)(bn2sc + c);
                f32x4 sh = *(const f32x4*)(bn2sh + c);
                u16x4 o;
#pragma unroll
                for (int j = 0; j < 4; ++j) {
                    float zv = (val[j] + tv[j]) * sc[j] + sh[j];
                    o[j] = f2bf(silu_d(zv));
                }
                *(u16x4*)(h2in + v * 128 + c) = o;
            }
        }
    }
}

// ================= conv2: ko-split-4 + residual on wave 3 =================
// out = sparseconv(h2in,W2) + bf16(x)@res_W + res_b
__global__ __launch_bounds__(256) void k_conv2(
        const unsigned short* __restrict__ h2in, const int* __restrict__ nbr,
        const unsigned char* __restrict__ mask, const unsigned short* __restrict__ W2s,
        const float* __restrict__ x, const unsigned short* __restrict__ rWs,
        const float* __restrict__ resb, float* __restrict__ out, int NV) {
    const int lane = threadIdx.x & 63;
    const int wave = threadIdx.x >> 6;
    const int g = lane >> 4, col = lane & 15;
    const int nb = blockIdx.x * 32;
    const int v0 = nb + col, v1 = nb + 16 + col;
    const int msh = mask_shift(mask, NV);
    const int sbeg = wave * 7;
    const int scnt = min(7, 27 - sbeg);

    f32x4 acc[2][8];
    const f32x4 z4 = {0.f, 0.f, 0.f, 0.f};
#pragma unroll
    for (int t = 0; t < 2; ++t)
#pragma unroll
        for (int m = 0; m < 8; ++m) acc[t][m] = z4;
    const s16x8 zz = {0, 0, 0, 0, 0, 0, 0, 0};

    int r0[7], r1[7];
#pragma unroll
    for (int s = 0; s < 7; ++s) {
        r0[s] = -1; r1[s] = -1;
        if (s < scnt) {
            int off = (sbeg + s) * NV;
            if (v0 < NV) {
                int nv = nbr[off + v0];
                bool mm = mask[(size_t)(off + v0) << msh] != 0;
                r0[s] = mm ? nv : -1;
            }
            if (v1 < NV) {
                int nv = nbr[off + v1];
                bool mm = mask[(size_t)(off + v1) << msh] != 0;
                r1[s] = mm ? nv : -1;
            }
        }
    }

#pragma unroll
    for (int s = 0; s < 7; ++s) {
        if (s < scnt) {
            const int ko = sbeg + s;
            const bool m0 = r0[s] >= 0, m1 = r1[s] >= 0;
            const int row0 = m0 ? r0[s] : 0, row1 = m1 ? r1[s] : 0;
#pragma unroll
            for (int ks = 0; ks < 4; ++ks) {
                s16x8 b0 = *(const s16x8*)(h2in + row0 * 128 + ks * 32 + g * 8);
                s16x8 b1 = *(const s16x8*)(h2in + row1 * 128 + ks * 32 + g * 8);
                b0 = m0 ? b0 : zz;
                b1 = m1 ? b1 : zz;
                const unsigned short* wp = W2s + (ko * 4 + ks) * 4096 + lane * 8;
#pragma unroll
                for (int mt = 0; mt < 8; ++mt) {
                    s16x8 a = *(const s16x8*)(wp + mt * 512);
                    acc[0][mt] = __builtin_amdgcn_mfma_f32_16x16x32_bf16(a, b0, acc[0][mt], 0, 0, 0);
                    acc[1][mt] = __builtin_amdgcn_mfma_f32_16x16x32_bf16(a, b1, acc[1][mt], 0, 0, 0);
                }
            }
        }
    }

    // residual GEMM on the light wave (wave 3 has only 6 conv steps)
    if (wave == 3) {
        int rr0 = (v0 < NV) ? v0 : 0;
        int rr1 = (v1 < NV) ? v1 : 0;
#pragma unroll
        for (int ks = 0; ks < 2; ++ks) {
            f32x4 xa0 = *(const f32x4*)(x + rr0 * 64 + ks * 32 + g * 8);
            f32x4 xb0 = *(const f32x4*)(x + rr0 * 64 + ks * 32 + g * 8 + 4);
            f32x4 xa1 = *(const f32x4*)(x + rr1 * 64 + ks * 32 + g * 8);
            f32x4 xb1 = *(const f32x4*)(x + rr1 * 64 + ks * 32 + g * 8 + 4);
            s16x8 b0, b1;
#pragma unroll
            for (int j = 0; j < 4; ++j) {
                b0[j]     = (short)f2bf(xa0[j]);
                b0[j + 4] = (short)f2bf(xb0[j]);
                b1[j]     = (short)f2bf(xa1[j]);
                b1[j + 4] = (short)f2bf(xb1[j]);
            }
            const unsigned short* wp = rWs + ks * 4096 + lane * 8;
#pragma unroll
            for (int mt = 0; mt < 8; ++mt) {
                s16x8 a = *(const s16x8*)(wp + mt * 512);
                acc[0][mt] = __builtin_amdgcn_mfma_f32_16x16x32_bf16(a, b0, acc[0][mt], 0, 0, 0);
                acc[1][mt] = __builtin_amdgcn_mfma_f32_16x16x32_bf16(a, b1, acc[1][mt], 0, 0, 0);
            }
        }
    }

    // ---- LDS tree reduce ----
    __shared__ float red[2][2][16 * RSTRIDE];
    const int lbase = col * RSTRIDE + g * 4;
    if (wave >= 2) {
        int p = wave - 2;
#pragma unroll
        for (int t = 0; t < 2; ++t)
#pragma unroll
            for (int mt = 0; mt < 8; ++mt)
                *(f32x4*)&red[p][t][lbase + mt * 16] = acc[t][mt];
    }
    __syncthreads();
    if (wave < 2) {
#pragma unroll
        for (int t = 0; t < 2; ++t)
#pragma unroll
            for (int mt = 0; mt < 8; ++mt)
                acc[t][mt] += *(const f32x4*)&red[wave][t][lbase + mt * 16];
    }
    __syncthreads();
    if (wave == 1) {
#pragma unroll
        for (int mt = 0; mt < 8; ++mt)
            *(f32x4*)&red[0][0][lbase + mt * 16] = acc[0][mt];
    } else if (wave == 0) {
#pragma unroll
        for (int mt = 0; mt < 8; ++mt)
            *(f32x4*)&red[0][1][lbase + mt * 16] = acc[1][mt];
    }
    __syncthreads();

    // ---- epilogue: wave0 -> tile0, wave1 -> tile1 ----
    if (wave < 2) {
        const int t = wave;
        int v = nb + t * 16 + col;
        if (v < NV) {
#pragma unroll
            for (int mt = 0; mt < 8; ++mt) {
                int c = mt * 16 + g * 4;
                f32x4 r = acc[t][mt] + *(const f32x4*)&red[0][t][lbase + mt * 16]
                        + *(const f32x4*)(resb + c);
                *(f32x4*)(out + v * 128 + c) = r;
            }
        }
    }
}

extern "C" void kernel_launch(void* const* d_in, const int* in_sizes, int n_in,
                              void* d_out, int out_size, void* d_ws, size_t ws_size,
                              hipStream_t stream) {
    const float* x          = (const float*)d_in[0];
    const int* bidx         = (const int*)d_in[1];
    const float* t          = (const float*)d_in[2];
    const int* nbr1         = (const int*)d_in[3];
    const unsigned char* mask1 = (const unsigned char*)d_in[4];
    const int* nbr2         = (const int*)d_in[5];
    const unsigned char* mask2 = (const unsigned char*)d_in[6];
    const float* bn1g       = (const float*)d_in[7];
    const float* bn1b       = (const float*)d_in[8];
    const float* bn1m       = (const float*)d_in[9];
    const float* bn1v       = (const float*)d_in[10];
    const float* W1         = (const float*)d_in[11];
    const float* tW         = (const float*)d_in[12];
    const float* tb         = (const float*)d_in[13];
    const float* bn2g       = (const float*)d_in[14];
    const float* bn2b       = (const float*)d_in[15];
    const float* bn2m       = (const float*)d_in[16];
    const float* bn2v       = (const float*)d_in[17];
    const float* W2         = (const float*)d_in[18];
    const float* rW         = (const float*)d_in[19];
    const float* resb       = (const float*)d_in[20];

    const int NV = in_sizes[0] / 64;
    const int B  = in_sizes[2] / 256;
    float* out = (float*)d_out;

    // workspace layout: small buffers first, total ~20.5 MB
    char* ws = (char*)d_ws;
    size_t o_W1s = 0;
    size_t o_W2s = o_W1s + (size_t)432 * 1024;
    size_t o_rWs = o_W2s + (size_t)864 * 1024;
    size_t o_te  = o_rWs + (size_t)16 * 1024;
    size_t o_sc  = o_te  + (size_t)B * 128 * 4;
    size_t o_sh  = o_sc  + 512;
    size_t o_h1  = o_sh  + 512;
    size_t o_h2  = o_h1  + (size_t)NV * 64 * 2;

    unsigned short* W1s  = (unsigned short*)(ws + o_W1s);
    unsigned short* W2s  = (unsigned short*)(ws + o_W2s);
    unsigned short* rWs  = (unsigned short*)(ws + o_rWs);
    float* temb  = (float*)(ws + o_te);
    float* bn2sc = (float*)(ws + o_sc);
    float* bn2sh = (float*)(ws + o_sh);
    unsigned short* h1   = (unsigned short*)(ws + o_h1);
    unsigned short* h2in = (unsigned short*)(ws + o_h2);

    k_prep_small<<<1, 512, 0, stream>>>(t, tW, tb, bn2g, bn2b, bn2m, bn2v,
                                        temb, bn2sc, bn2sh, B);
    {
        int total = (432 + 864 + 16) * 512;
        int grid = (total + 255) / 256;
        k_shuffle<<<grid, 256, 0, stream>>>(W1, W2, rW, W1s, W2s, rWs);
    }
    {
        int total = NV * 16;
        int grid = (total + 255) / 256;
        k_elem<<<grid, 256, 0, stream>>>(x, bn1g, bn1b, bn1m, bn1v, h1, NV);
    }
    {
        int grid = (NV + 31) / 32;
        k_conv1<<<grid, 256, 0, stream>>>(h1, nbr1, mask1, W1s, temb, bidx,
                                          bn2sc, bn2sh, h2in, NV);
        k_conv2<<<grid, 256, 0, stream>>>(h2in, nbr2, mask2, W2s, x, rWs,
                                          resb, out, NV);
    }
}

// Round 13
// 168.877 us; speedup vs baseline: 2.6723x; 2.6723x over previous
//
#include <hip/hip_runtime.h>

// SparseResidualBlock: bn1->silu->sparseconv1(+t_emb)->bn2->silu->sparseconv2 + (x@res_W+res_b)
// N=50000, FIN=64, FOUT=128, K=27, B=4, TEMB=256. Output f32 [N,128].
//
// R13 = R8 + half-tap double-buffered pipeline at CONSTANT 32KB LDS:
// period = 16KB weight chunk (conv1: 1 tap, 27 periods; conv2: half tap, 54).
// Per period: issue stage(p+1) into idle 16KB buffer + prefetch next gathers
// to regs, compute 16 MFMAs from live buffer, ONE barrier. Stage+gather
// latency hides under compute; occupancy unchanged vs R8 (R10 lesson).
// Ko-split abandoned (R12: structural spill). No NT loads (R6).

#define EPS 1e-5f

typedef __attribute__((ext_vector_type(8))) short s16x8;
typedef __attribute__((ext_vector_type(4))) float f32x4;
typedef __attribute__((ext_vector_type(4))) unsigned short u16x4;

static __device__ __forceinline__ unsigned short f2bf(float f) {
    union { float f; unsigned u; } v; v.f = f;
    unsigned r = v.u + 0x7fffu + ((v.u >> 16) & 1u);   // RTNE
    return (unsigned short)(r >> 16);
}
static __device__ __forceinline__ float silu_d(float x) {
    return x / (1.f + __expf(-x));
}
// direct global->LDS copy, 16B per lane
static __device__ __forceinline__ void gload_lds16(const void* gsrc, void* ldst) {
    __builtin_amdgcn_global_load_lds(
        (const __attribute__((address_space(1))) unsigned int*)gsrc,
        (__attribute__((address_space(3))) unsigned int*)ldst, 16, 0, 0);
}
// mask stored as 1-byte bool (shift 0) or int32 (shift 2)? Probe a byte at a
// non-multiple-of-4 index inside the all-true center row (k=13).
static __device__ __forceinline__ int mask_shift(const unsigned char* mask, int NV) {
    size_t base = (size_t)13 * (size_t)NV;
    int v = ((base & 3) == 3) ? 2 : 1;
    return (mask[base + v] == 1) ? 0 : 2;
}

// ---------------- prep: t_emb + bn2 scale/shift ----------------
__global__ void k_prep_small(const float* __restrict__ t, const float* __restrict__ tW,
                             const float* __restrict__ tb,
                             const float* __restrict__ g2, const float* __restrict__ b2,
                             const float* __restrict__ m2, const float* __restrict__ v2,
                             float* __restrict__ temb, float* __restrict__ sc,
                             float* __restrict__ sh, int B) {
    int tid = threadIdx.x;
    if (tid < B * 128) {
        int b = tid >> 7, o = tid & 127;
        float s = 0.f;
        for (int e = 0; e < 256; ++e) {
            float tv = t[b * 256 + e];
            s += silu_d(tv) * tW[e * 128 + o];
        }
        temb[tid] = s + tb[o];
    }
    if (tid < 128) {
        float rstd = rsqrtf(v2[tid] + EPS);
        float s1 = g2[tid] * rstd;
        sc[tid] = s1;
        sh[tid] = b2[tid] - m2[tid] * s1;
    }
}

// ---------------- prep: shuffle weights to fragment-linear bf16 (16x16x32) ----------------
// frag elem[lane*8+j] = W[ko][fin=ks*32+(lane>>4)*8+j][fout=mt*16+(lane&15)]
__global__ __launch_bounds__(256) void k_shuffle(
        const float* __restrict__ W1, const float* __restrict__ W2,
        const float* __restrict__ rW,
        unsigned short* __restrict__ W1s, unsigned short* __restrict__ W2s,
        unsigned short* __restrict__ rWs) {
    int tid = blockIdx.x * 256 + threadIdx.x;
    const int n1 = 432 * 512, n2 = 864 * 512, n3 = 16 * 512;
    if (tid < n1) {
        int f = tid >> 9, r = tid & 511, lane = r >> 3, j = r & 7;
        int mt = f & 7, fk = f >> 3, ks = fk & 1, ko = fk >> 1;
        int fin = ks * 32 + (lane >> 4) * 8 + j;
        int fout = mt * 16 + (lane & 15);
        W1s[tid] = f2bf(W1[(ko * 64 + fin) * 128 + fout]);
    } else if (tid < n1 + n2) {
        int e = tid - n1;
        int f = e >> 9, r = e & 511, lane = r >> 3, j = r & 7;
        int mt = f & 7, fk = f >> 3, ks = fk & 3, ko = fk >> 2;
        int fin = ks * 32 + (lane >> 4) * 8 + j;
        int fout = mt * 16 + (lane & 15);
        W2s[e] = f2bf(W2[(ko * 128 + fin) * 128 + fout]);
    } else if (tid < n1 + n2 + n3) {
        int e = tid - n1 - n2;
        int f = e >> 9, r = e & 511, lane = r >> 3, j = r & 7;
        int mt = f & 7, ks = f >> 3;
        int fin = ks * 32 + (lane >> 4) * 8 + j;
        int fout = mt * 16 + (lane & 15);
        rWs[e] = f2bf(rW[fin * 128 + fout]);
    }
}

// ---------------- elementwise: h1 = bf16(silu(bn1(x))) ----------------
__global__ __launch_bounds__(256) void k_elem(
        const float* __restrict__ x,
        const float* __restrict__ g1, const float* __restrict__ b1,
        const float* __restrict__ m1, const float* __restrict__ v1,
        unsigned short* __restrict__ h1, int NV) {
    int tid = blockIdx.x * 256 + threadIdx.x;
    if (tid >= NV * 16) return;
    int n = tid >> 4, c = (tid & 15) << 2;
    f32x4 xv = *(const f32x4*)(x + n * 64 + c);
    f32x4 gv = *(const f32x4*)(g1 + c);
    f32x4 bv = *(const f32x4*)(b1 + c);
    f32x4 mv = *(const f32x4*)(m1 + c);
    f32x4 vv = *(const f32x4*)(v1 + c);
    u16x4 ho;
#pragma unroll
    for (int j = 0; j < 4; ++j) {
        float xn = (xv[j] - mv[j]) * rsqrtf(vv[j] + EPS) * gv[j] + bv[j];
        ho[j] = f2bf(silu_d(xn));
    }
    *(u16x4*)(h1 + n * 64 + c) = ho;
}

// ================= conv1: 27-period dbuf pipeline (1 tap = 16KB chunk) =================
// h2in = bf16(silu(bn2(sparseconv(h1,W1) + temb[bidx])))
__global__ __launch_bounds__(256) void k_conv1(
        const unsigned short* __restrict__ h1, const int* __restrict__ nbr,
        const unsigned char* __restrict__ mask, const unsigned short* __restrict__ W1s,
        const float* __restrict__ temb, const int* __restrict__ bidx,
        const float* __restrict__ bn2sc, const float* __restrict__ bn2sh,
        unsigned short* __restrict__ h2in, int NV) {
    __shared__ unsigned short ldsW[2][8192];   // 2 x 16KB
    const int lane = threadIdx.x & 63;
    const int wave = threadIdx.x >> 6;
    const int g = lane >> 4, col = lane & 15;
    const int v = blockIdx.x * 64 + wave * 16 + col;
    const bool vok = v < NV;
    const int msh = mask_shift(mask, NV);

    int r[27];
#pragma unroll
    for (int s = 0; s < 27; ++s) {
        r[s] = -1;
        if (vok) {
            int off = s * NV + v;
            int nv = nbr[off];
            bool mm = mask[(size_t)off << msh] != 0;
            r[s] = mm ? nv : -1;
        }
    }

    f32x4 acc[8];
    const f32x4 z4 = {0.f, 0.f, 0.f, 0.f};
#pragma unroll
    for (int m = 0; m < 8; ++m) acc[m] = z4;
    const s16x8 zz = {0, 0, 0, 0, 0, 0, 0, 0};

    // prologue: stage period 0 into buf0, gather tap 0
    {
        const char* src = (const char*)W1s + (size_t)threadIdx.x * 16;
        char* dst = (char*)&ldsW[0][0] + (size_t)threadIdx.x * 16;
#pragma unroll
        for (int i = 0; i < 4; ++i)
            gload_lds16(src + i * 4096, dst + i * 4096);
    }
    int row0 = (r[0] >= 0) ? r[0] : 0;
    s16x8 c0 = *(const s16x8*)(h1 + row0 * 64 + 0 * 32 + g * 8);
    s16x8 c1 = *(const s16x8*)(h1 + row0 * 64 + 1 * 32 + g * 8);
    __syncthreads();   // stage0 + gather0 complete

#pragma unroll
    for (int s = 0; s < 27; ++s) {
        // issue next period's stage (into idle buffer) + gather prefetch
        s16x8 n0, n1;
        if (s < 26) {
            const char* src = (const char*)W1s + (size_t)(s + 1) * 16384 + (size_t)threadIdx.x * 16;
            char* dst = (char*)&ldsW[(s + 1) & 1][0] + (size_t)threadIdx.x * 16;
#pragma unroll
            for (int i = 0; i < 4; ++i)
                gload_lds16(src + i * 4096, dst + i * 4096);
            int rn = (r[s + 1] >= 0) ? r[s + 1] : 0;
            n0 = *(const s16x8*)(h1 + rn * 64 + 0 * 32 + g * 8);
            n1 = *(const s16x8*)(h1 + rn * 64 + 1 * 32 + g * 8);
        }
        // compute tap s from live buffer
        const bool m = r[s] >= 0;
        s16x8 b0 = m ? c0 : zz;
        s16x8 b1 = m ? c1 : zz;
        const unsigned short* wp = &ldsW[s & 1][0] + lane * 8;
#pragma unroll
        for (int mt = 0; mt < 8; ++mt) {
            s16x8 a = *(const s16x8*)(wp + (0 * 8 + mt) * 512);
            acc[mt] = __builtin_amdgcn_mfma_f32_16x16x32_bf16(a, b0, acc[mt], 0, 0, 0);
        }
#pragma unroll
        for (int mt = 0; mt < 8; ++mt) {
            s16x8 a = *(const s16x8*)(wp + (1 * 8 + mt) * 512);
            acc[mt] = __builtin_amdgcn_mfma_f32_16x16x32_bf16(a, b1, acc[mt], 0, 0, 0);
        }
        if (s < 26) {
            __syncthreads();   // ONE barrier: stage(s+1)+gather(s+1) done, reads(s) done
            c0 = n0; c1 = n1;
        }
    }

    if (vok) {
        int b = bidx[v];
        const float* te = temb + b * 128;
#pragma unroll
        for (int mt = 0; mt < 8; ++mt) {
            int c = mt * 16 + g * 4;
            f32x4 val = acc[mt];
            f32x4 tv = *(const f32x4*)(te + c);
            f32x4 sc = *(const f32x4*)(bn2sc + c);
            f32x4 sh = *(const f32x4*)(bn2sh + c);
            u16x4 o;
#pragma unroll
            for (int j = 0; j < 4; ++j) {
                float zv = (val[j] + tv[j]) * sc[j] + sh[j];
                o[j] = f2bf(silu_d(zv));
            }
            *(u16x4*)(h2in + v * 128 + c) = o;
        }
    }
}

// ================= conv2: 54-period dbuf pipeline (half tap = 16KB chunk) =================
// out = sparseconv(h2in,W2) + bf16(x)@res_W + res_b
__global__ __launch_bounds__(256) void k_conv2(
        const unsigned short* __restrict__ h2in, const int* __restrict__ nbr,
        const unsigned char* __restrict__ mask, const unsigned short* __restrict__ W2s,
        const float* __restrict__ x, const unsigned short* __restrict__ rWs,
        const float* __restrict__ resb, float* __restrict__ out, int NV) {
    __shared__ unsigned short ldsW[2][8192];   // 2 x 16KB
    const int lane = threadIdx.x & 63;
    const int wave = threadIdx.x >> 6;
    const int g = lane >> 4, col = lane & 15;
    const int v = blockIdx.x * 64 + wave * 16 + col;
    const bool vok = v < NV;
    const int msh = mask_shift(mask, NV);

    int r[27];
#pragma unroll
    for (int s = 0; s < 27; ++s) {
        r[s] = -1;
        if (vok) {
            int off = s * NV + v;
            int nv = nbr[off];
            bool mm = mask[(size_t)off << msh] != 0;
            r[s] = mm ? nv : -1;
        }
    }

    f32x4 acc[8];
    const f32x4 z4 = {0.f, 0.f, 0.f, 0.f};
#pragma unroll
    for (int m = 0; m < 8; ++m) acc[m] = z4;
    const s16x8 zz = {0, 0, 0, 0, 0, 0, 0, 0};

    // prologue: stage period 0 (tap0 first half), gather tap0 ks{0,1}
    {
        const char* src = (const char*)W2s + (size_t)threadIdx.x * 16;
        char* dst = (char*)&ldsW[0][0] + (size_t)threadIdx.x * 16;
#pragma unroll
        for (int i = 0; i < 4; ++i)
            gload_lds16(src + i * 4096, dst + i * 4096);
    }
    int row0 = (r[0] >= 0) ? r[0] : 0;
    s16x8 c0 = *(const s16x8*)(h2in + row0 * 128 + 0 * 32 + g * 8);
    s16x8 c1 = *(const s16x8*)(h2in + row0 * 128 + 1 * 32 + g * 8);

    // residual GEMM while period 0 stages (global rWs, tiny & L2-hot)
    {
        int rv = vok ? v : 0;
#pragma unroll
        for (int ks = 0; ks < 2; ++ks) {
            f32x4 xa = *(const f32x4*)(x + rv * 64 + ks * 32 + g * 8);
            f32x4 xb = *(const f32x4*)(x + rv * 64 + ks * 32 + g * 8 + 4);
            s16x8 b;
#pragma unroll
            for (int j = 0; j < 4; ++j) {
                b[j]     = (short)f2bf(xa[j]);
                b[j + 4] = (short)f2bf(xb[j]);
            }
            const unsigned short* wp = rWs + ks * 4096 + lane * 8;
#pragma unroll
            for (int mt = 0; mt < 8; ++mt) {
                s16x8 a = *(const s16x8*)(wp + mt * 512);
                acc[mt] = __builtin_amdgcn_mfma_f32_16x16x32_bf16(a, b, acc[mt], 0, 0, 0);
            }
        }
    }
    __syncthreads();   // period 0 staged + gathered

    // 54 periods: period p = tap (p>>1), half (p&1) -> ks = 2*(p&1), 2*(p&1)+1
#pragma unroll
    for (int p = 0; p < 54; ++p) {
        s16x8 n0, n1;
        if (p < 53) {
            const int pn = p + 1;
            const char* src = (const char*)W2s + (size_t)pn * 16384 + (size_t)threadIdx.x * 16;
            char* dst = (char*)&ldsW[pn & 1][0] + (size_t)threadIdx.x * 16;
#pragma unroll
            for (int i = 0; i < 4; ++i)
                gload_lds16(src + i * 4096, dst + i * 4096);
            const int tn = pn >> 1, hn = pn & 1;
            int rn = (r[tn] >= 0) ? r[tn] : 0;
            n0 = *(const s16x8*)(h2in + rn * 128 + (hn * 2 + 0) * 32 + g * 8);
            n1 = *(const s16x8*)(h2in + rn * 128 + (hn * 2 + 1) * 32 + g * 8);
        }
        const int tp = p >> 1;
        const bool m = r[tp] >= 0;
        s16x8 b0 = m ? c0 : zz;
        s16x8 b1 = m ? c1 : zz;
        const unsigned short* wp = &ldsW[p & 1][0] + lane * 8;
#pragma unroll
        for (int mt = 0; mt < 8; ++mt) {
            s16x8 a = *(const s16x8*)(wp + (0 * 8 + mt) * 512);
            acc[mt] = __builtin_amdgcn_mfma_f32_16x16x32_bf16(a, b0, acc[mt], 0, 0, 0);
        }
#pragma unroll
        for (int mt = 0; mt < 8; ++mt) {
            s16x8 a = *(const s16x8*)(wp + (1 * 8 + mt) * 512);
            acc[mt] = __builtin_amdgcn_mfma_f32_16x16x32_bf16(a, b1, acc[mt], 0, 0, 0);
        }
        if (p < 53) {
            __syncthreads();   // ONE barrier per period
            c0 = n0; c1 = n1;
        }
    }

    if (vok) {
#pragma unroll
        for (int mt = 0; mt < 8; ++mt) {
            int c = mt * 16 + g * 4;
            f32x4 rr = acc[mt] + *(const f32x4*)(resb + c);
            *(f32x4*)(out + v * 128 + c) = rr;
        }
    }
}

extern "C" void kernel_launch(void* const* d_in, const int* in_sizes, int n_in,
                              void* d_out, int out_size, void* d_ws, size_t ws_size,
                              hipStream_t stream) {
    const float* x          = (const float*)d_in[0];
    const int* bidx         = (const int*)d_in[1];
    const float* t          = (const float*)d_in[2];
    const int* nbr1         = (const int*)d_in[3];
    const unsigned char* mask1 = (const unsigned char*)d_in[4];
    const int* nbr2         = (const int*)d_in[5];
    const unsigned char* mask2 = (const unsigned char*)d_in[6];
    const float* bn1g       = (const float*)d_in[7];
    const float* bn1b       = (const float*)d_in[8];
    const float* bn1m       = (const float*)d_in[9];
    const float* bn1v       = (const float*)d_in[10];
    const float* W1         = (const float*)d_in[11];
    const float* tW         = (const float*)d_in[12];
    const float* tb         = (const float*)d_in[13];
    const float* bn2g       = (const float*)d_in[14];
    const float* bn2b       = (const float*)d_in[15];
    const float* bn2m       = (const float*)d_in[16];
    const float* bn2v       = (const float*)d_in[17];
    const float* W2         = (const float*)d_in[18];
    const float* rW         = (const float*)d_in[19];
    const float* resb       = (const float*)d_in[20];

    const int NV = in_sizes[0] / 64;
    const int B  = in_sizes[2] / 256;
    float* out = (float*)d_out;

    // workspace layout: small buffers first, total ~20.5 MB
    char* ws = (char*)d_ws;
    size_t o_W1s = 0;
    size_t o_W2s = o_W1s + (size_t)432 * 1024;
    size_t o_rWs = o_W2s + (size_t)864 * 1024;
    size_t o_te  = o_rWs + (size_t)16 * 1024;
    size_t o_sc  = o_te  + (size_t)B * 128 * 4;
    size_t o_sh  = o_sc  + 512;
    size_t o_h1  = o_sh  + 512;
    size_t o_h2  = o_h1  + (size_t)NV * 64 * 2;

    unsigned short* W1s  = (unsigned short*)(ws + o_W1s);
    unsigned short* W2s  = (unsigned short*)(ws + o_W2s);
    unsigned short* rWs  = (unsigned short*)(ws + o_rWs);
    float* temb  = (float*)(ws + o_te);
    float* bn2sc = (float*)(ws + o_sc);
    float* bn2sh = (float*)(ws + o_sh);
    unsigned short* h1   = (unsigned short*)(ws + o_h1);
    unsigned short* h2in = (unsigned short*)(ws + o_h2);

    k_prep_small<<<1, 512, 0, stream>>>(t, tW, tb, bn2g, bn2b, bn2m, bn2v,
                                        temb, bn2sc, bn2sh, B);
    {
        int total = (432 + 864 + 16) * 512;
        int grid = (total + 255) / 256;
        k_shuffle<<<grid, 256, 0, stream>>>(W1, W2, rW, W1s, W2s, rWs);
    }
    {
        int total = NV * 16;
        int grid = (total + 255) / 256;
        k_elem<<<grid, 256, 0, stream>>>(x, bn1g, bn1b, bn1m, bn1v, h1, NV);
    }
    {
        int grid = (NV + 63) / 64;
        k_conv1<<<grid, 256, 0, stream>>>(h1, nbr1, mask1, W1s, temb, bidx,
                                          bn2sc, bn2sh, h2in, NV);
        k_conv2<<<grid, 256, 0, stream>>>(h2in, nbr2, mask2, W2s, x, rWs,
                                          resb, out, NV);
    }
}